// Round 1
// baseline (1489.612 us; speedup 1.0000x reference)
//
#include <hip/hip_runtime.h>
#include <math.h>

// Problem constants: B=8, H=16, N=1024, D=1024, hd=64
// ws layout (floats): q at 0, k at +QSZ, v at +2*QSZ  (QSZ = B*H*N*hd = 8M floats)
// attention output O overwrites the q region in (B,H,N,hd) layout (each block
// writes only the rows it exclusively read -> no cross-block race).
// ws requirement: 96 MB.
#define QSZ 8388608

// ---------------------------------------------------------------------------
// Generic 64x64-tile fp32 GEMM, BK=16, 4x4 microtiles, 256 threads.
// MODE 0: A = x [8192,1024] row-major; epilogue scatters C into q/k/v
//         (B,H,N,hd) buffers in ws. Nn = 3072.
// MODE 1: A = O in (B,H,N,hd) layout (remapped on load); epilogue writes
//         plain row-major C [8192, Nn]. Nn = 1024.
// ---------------------------------------------------------------------------
template<int MODE>
__global__ __launch_bounds__(256)
void gemm_k(const float* __restrict__ A, const float* __restrict__ Bm,
            const float* __restrict__ bias, float* __restrict__ C,
            const int K, const int Nn) {
  __shared__ float At[16][68];  // A transposed: At[k][m]
  __shared__ float Bl[16][68];  // B direct:     Bl[k][n]
  const int t  = threadIdx.x;
  const int bm = blockIdx.y, bn = blockIdx.x;
  const int i0 = (t >> 4) << 2;      // microtile row base (0..60)
  const int j0 = (t & 15) << 2;      // microtile col base (0..60)
  const int arow = t >> 2,  ac = (t & 3) << 2;   // A staging: row 0..63, col 0/4/8/12
  const int brow = t >> 4,  bc = (t & 15) << 2;  // B staging: row 0..15, col 0..60

  float acc[4][4] = {};

  for (int kk = 0; kk < K; kk += 16) {
    // ---- stage A (transposed into LDS) ----
    float4 av;
    if (MODE == 0) {
      av = *(const float4*)&A[(bm * 64 + arow) * K + kk + ac];
    } else {
      // A is O in (B,H,N,hd): row m=b*1024+n, col=h*64+d
      const int m = bm * 64 + arow, col = kk + ac;
      const int b = m >> 10, n = m & 1023, h = col >> 6, d = col & 63;
      av = *(const float4*)&A[b * 1048576 + h * 65536 + n * 64 + d];
    }
    At[ac + 0][arow] = av.x;
    At[ac + 1][arow] = av.y;
    At[ac + 2][arow] = av.z;
    At[ac + 3][arow] = av.w;
    // ---- stage B ----
    *(float4*)&Bl[brow][bc] =
        *(const float4*)&Bm[(kk + brow) * Nn + bn * 64 + bc];
    __syncthreads();

#pragma unroll
    for (int c = 0; c < 16; ++c) {
      const float4 a4 = *(const float4*)&At[c][i0];
      const float4 b4 = *(const float4*)&Bl[c][j0];
      const float a[4] = {a4.x, a4.y, a4.z, a4.w};
      const float b[4] = {b4.x, b4.y, b4.z, b4.w};
#pragma unroll
      for (int ii = 0; ii < 4; ++ii)
#pragma unroll
        for (int jj = 0; jj < 4; ++jj)
          acc[ii][jj] = fmaf(a[ii], b[jj], acc[ii][jj]);
    }
    __syncthreads();
  }

  const float4 bb = *(const float4*)&bias[bn * 64 + j0];
  const float bias4[4] = {bb.x, bb.y, bb.z, bb.w};

  if (MODE == 0) {
    // tile's 64-col span is exactly one (t,h) pair: t = bn/16, h = bn%16
    const int tq = bn >> 4, h = bn & 15;
    float* dst = C + tq * QSZ;
#pragma unroll
    for (int ii = 0; ii < 4; ++ii) {
      const int m = bm * 64 + i0 + ii;
      const int b = m >> 10, n = m & 1023;
      float4 o;
      o.x = acc[ii][0] + bias4[0];
      o.y = acc[ii][1] + bias4[1];
      o.z = acc[ii][2] + bias4[2];
      o.w = acc[ii][3] + bias4[3];
      *(float4*)&dst[((b * 16 + h) * 1024 + n) * 64 + j0] = o;
    }
  } else {
#pragma unroll
    for (int ii = 0; ii < 4; ++ii) {
      const int m = bm * 64 + i0 + ii;
      float4 o;
      o.x = acc[ii][0] + bias4[0];
      o.y = acc[ii][1] + bias4[1];
      o.z = acc[ii][2] + bias4[2];
      o.w = acc[ii][3] + bias4[3];
      *(float4*)&C[m * Nn + bn * 64 + j0] = o;
    }
  }
}

// ---------------------------------------------------------------------------
// RMSNorm + 2D-RoPE applied in place to q and k buffers, one wave per head row.
// rows 0..131071 -> q, 131072..262143 -> k
// ---------------------------------------------------------------------------
__global__ __launch_bounds__(256)
void rmsrope_k(float* __restrict__ W, const float* __restrict__ qs,
               const float* __restrict__ ks) {
  const int t = threadIdx.x;
  const int lane = t & 63;
  const int row = blockIdx.x * 4 + (t >> 6);  // 0..262143
  const int which = row >> 17;                // 0=q, 1=k
  const int r = row & 131071;                 // (b*16+h)*1024 + n
  float* buf = W + which * QSZ + r * 64;
  const float* sc = which ? ks : qs;

  const float v = buf[lane];
  float ss = v * v;
#pragma unroll
  for (int off = 32; off; off >>= 1) ss += __shfl_xor(ss, off, 64);
  const float sv = v * rsqrtf(ss * (1.0f / 64.0f) + 1e-6f) * sc[lane];

  // 2D RoPE: n -> (n/32, n%32); angle dims: j<16 row-part, j>=16 col-part
  const int n = r & 1023;
  const int j = lane & 31;
  const int idx = j & 15;
  const float invf = expf(-(float)idx * 0.57564627324851149f);  // ln(1e4)/16
  const float pos = (j < 16) ? (float)(n >> 5) : (float)(n & 31);
  const float ang = pos * invf;
  const float cs = cosf(ang), sn = sinf(ang);
  const float other = __shfl_xor(sv, 32, 64);
  const float res = (lane < 32) ? (sv * cs - other * sn)
                                : (other * sn + sv * cs);
  buf[lane] = res;
}

// ---------------------------------------------------------------------------
// Flash-style attention, fp32 vector. One block per (b,h,64-row Q tile).
// Online softmax; O overwrites this block's own Q rows at the end.
// ---------------------------------------------------------------------------
__global__ __launch_bounds__(256)
void attn_k(float* __restrict__ W) {
  float* q = W;                      // also O destination
  const float* k = W + QSZ;
  const float* v = W + 2 * QSZ;

  __shared__ float qT[64][68];   // qT[d][i]
  __shared__ float kT[64][68];   // kT[d][j]
  __shared__ float vS[64][68];   // vS[j][d]
  __shared__ float pT[64][68];   // pT[j][i]: raw scores, then probs
  __shared__ float mrow[64], lrow[64], arow_s[64];
  __shared__ float red[4][64];

  const int t = threadIdx.x;
  const int qt = blockIdx.x, bh = blockIdx.y;
  const int i0 = (t >> 4) << 2;   // q-row microtile base
  const int j0 = (t & 15) << 2;   // k-col / v-dim microtile base
  const int seg = t >> 6, rr = t & 63;

  float* qbase = q + (bh * 1024 + qt * 64) * 64;

  // load Q tile transposed
#pragma unroll
  for (int it = 0; it < 4; ++it) {
    const int f = it * 256 + t;
    const int row = f >> 4, c4 = (f & 15) << 2;
    const float4 g = *(const float4*)&qbase[row * 64 + c4];
    qT[c4 + 0][row] = g.x;
    qT[c4 + 1][row] = g.y;
    qT[c4 + 2][row] = g.z;
    qT[c4 + 3][row] = g.w;
  }
  if (t < 64) { mrow[t] = -INFINITY; lrow[t] = 0.0f; }
  float o_acc[4][4] = {};
  __syncthreads();

  for (int kc = 0; kc < 16; ++kc) {
    const float* kbase = k + (bh * 1024 + kc * 64) * 64;
    const float* vbase = v + (bh * 1024 + kc * 64) * 64;
#pragma unroll
    for (int it = 0; it < 4; ++it) {
      const int f = it * 256 + t;
      const int row = f >> 4, c4 = (f & 15) << 2;
      const float4 g = *(const float4*)&kbase[row * 64 + c4];
      kT[c4 + 0][row] = g.x;
      kT[c4 + 1][row] = g.y;
      kT[c4 + 2][row] = g.z;
      kT[c4 + 3][row] = g.w;
      *(float4*)&vS[row][c4] = *(const float4*)&vbase[row * 64 + c4];
    }
    __syncthreads();  // (A) tiles staged

    // S = Q K^T * scale, 4x4 microtile per thread
    float s[4][4] = {};
#pragma unroll 8
    for (int d = 0; d < 64; ++d) {
      const float4 a4 = *(const float4*)&qT[d][i0];
      const float4 b4 = *(const float4*)&kT[d][j0];
      const float a[4] = {a4.x, a4.y, a4.z, a4.w};
      const float b[4] = {b4.x, b4.y, b4.z, b4.w};
#pragma unroll
      for (int ii = 0; ii < 4; ++ii)
#pragma unroll
        for (int jj = 0; jj < 4; ++jj)
          s[ii][jj] = fmaf(a[ii], b[jj], s[ii][jj]);
    }
#pragma unroll
    for (int ii = 0; ii < 4; ++ii)
#pragma unroll
      for (int jj = 0; jj < 4; ++jj)
        pT[j0 + jj][i0 + ii] = s[ii][jj] * 0.125f;
    __syncthreads();  // (B) raw scores in pT

    // chunk row-max (4 segments of 16 j each)
    float cm = -INFINITY;
    for (int jj = 0; jj < 16; ++jj) cm = fmaxf(cm, pT[seg * 16 + jj][rr]);
    red[seg][rr] = cm;
    __syncthreads();  // (C)

    if (t < 64) {
      const float c2 = fmaxf(fmaxf(red[0][t], red[1][t]),
                             fmaxf(red[2][t], red[3][t]));
      const float mo = mrow[t];
      const float mn = fmaxf(mo, c2);
      arow_s[t] = __expf(mo - mn);  // 0 on first chunk (mo=-inf)
      mrow[t] = mn;
    }
    __syncthreads();  // (D)

    // exponentiate in place, partial sums
    {
      const float mn = mrow[rr];
      float psum = 0.0f;
      for (int jj = 0; jj < 16; ++jj) {
        const int j = seg * 16 + jj;
        const float p = __expf(pT[j][rr] - mn);
        pT[j][rr] = p;
        psum += p;
      }
      red[seg][rr] = psum;
    }
    __syncthreads();  // (E) probs final

    if (t < 64)
      lrow[t] = arow_s[t] * lrow[t] +
                red[0][t] + red[1][t] + red[2][t] + red[3][t];

    // O = alpha*O + P V, 4x4 microtile (rows i0.., dims j0..)
    float al[4];
#pragma unroll
    for (int ii = 0; ii < 4; ++ii) al[ii] = arow_s[i0 + ii];
#pragma unroll
    for (int ii = 0; ii < 4; ++ii)
#pragma unroll
      for (int dd = 0; dd < 4; ++dd) o_acc[ii][dd] *= al[ii];
#pragma unroll 8
    for (int j = 0; j < 64; ++j) {
      const float4 p4 = *(const float4*)&pT[j][i0];
      const float4 v4 = *(const float4*)&vS[j][j0];
      const float p[4] = {p4.x, p4.y, p4.z, p4.w};
      const float vv[4] = {v4.x, v4.y, v4.z, v4.w};
#pragma unroll
      for (int ii = 0; ii < 4; ++ii)
#pragma unroll
        for (int dd = 0; dd < 4; ++dd)
          o_acc[ii][dd] = fmaf(p[ii], vv[dd], o_acc[ii][dd]);
    }
    __syncthreads();  // (F) end of chunk
  }

  // normalize and write O over own Q rows
#pragma unroll
  for (int ii = 0; ii < 4; ++ii) {
    const float linv = 1.0f / lrow[i0 + ii];
    float4 o;
    o.x = o_acc[ii][0] * linv;
    o.y = o_acc[ii][1] * linv;
    o.z = o_acc[ii][2] * linv;
    o.w = o_acc[ii][3] * linv;
    *(float4*)&qbase[(i0 + ii) * 64 + j0] = o;
  }
}

extern "C" void kernel_launch(void* const* d_in, const int* in_sizes, int n_in,
                              void* d_out, int out_size, void* d_ws,
                              size_t ws_size, hipStream_t stream) {
  const float* x    = (const float*)d_in[0];
  const float* Wqkv = (const float*)d_in[1];
  const float* bqkv = (const float*)d_in[2];
  const float* Wout = (const float*)d_in[3];
  const float* bout = (const float*)d_in[4];
  const float* qs   = (const float*)d_in[5];
  const float* ks   = (const float*)d_in[6];
  float* out = (float*)d_out;
  float* W = (float*)d_ws;  // needs 96 MB

  // 1) QKV GEMM + bias, scatter into q/k/v (B,H,N,hd)
  gemm_k<0><<<dim3(48, 128), 256, 0, stream>>>(x, Wqkv, bqkv, W, 1024, 3072);
  // 2) RMSNorm + RoPE on q and k in place
  rmsrope_k<<<65536, 256, 0, stream>>>(W, qs, ks);
  // 3) attention; O overwrites q region
  attn_k<<<dim3(16, 128), 256, 0, stream>>>(W);
  // 4) output projection
  gemm_k<1><<<dim3(16, 128), 256, 0, stream>>>(W, Wout, bout, out, 1024, 1024);
}

// Round 2
// 780.819 us; speedup vs baseline: 1.9078x; 1.9078x over previous
//
#include <hip/hip_runtime.h>
#include <hip/hip_bf16.h>
#include <math.h>

// B=8, H=16, N=1024, D=1024, hd=64
// ws layout (float units):
//   q  [0, 8M)   k [8M,16M)   v [16M,24M)          (fp32, 96 MB)
//   xb [24M,28M) as bf16 (8M elems)  -- reused as ob (bf16 O, row-major) after gemm1
//   WqkvT [28M,29.5M) as bf16 (3M elems, [3072,1024] = B^T)
//   WoutT [29.5M,30M) as bf16 (1M elems, [1024,1024] = B^T)
// total ws: 120 MB
#define QSZ 8388608

typedef short bf16x8 __attribute__((ext_vector_type(8)));
typedef float f32x4 __attribute__((ext_vector_type(4)));

__device__ __forceinline__ unsigned short f2bf(float f) {
  __hip_bfloat16 h = __float2bfloat16(f);
  return *reinterpret_cast<unsigned short*>(&h);
}

__device__ __forceinline__ void gload_lds16(const unsigned short* g,
                                            unsigned short* l) {
  __builtin_amdgcn_global_load_lds(
      (const __attribute__((address_space(1))) void*)g,
      (__attribute__((address_space(3))) void*)l, 16, 0, 0);
}

// ---------------------------------------------------------------------------
// fp32 -> bf16 elementwise convert, 8 elems/thread
// ---------------------------------------------------------------------------
__global__ __launch_bounds__(256)
void cvt_bf16(const float* __restrict__ src, unsigned short* __restrict__ dst) {
  const int i = (blockIdx.x * 256 + threadIdx.x) * 8;
  const float4 a = *(const float4*)&src[i];
  const float4 b = *(const float4*)&src[i + 4];
  ushort4 lo, hi;
  lo.x = f2bf(a.x); lo.y = f2bf(a.y); lo.z = f2bf(a.z); lo.w = f2bf(a.w);
  hi.x = f2bf(b.x); hi.y = f2bf(b.y); hi.z = f2bf(b.z); hi.w = f2bf(b.w);
  *(ushort4*)&dst[i] = lo;
  *(ushort4*)&dst[i + 4] = hi;
}

// ---------------------------------------------------------------------------
// transpose + convert: src [1024, N] fp32 -> dst [N, 1024] bf16 (32x32 tiles)
// ---------------------------------------------------------------------------
__global__ __launch_bounds__(256)
void cvt_t(const float* __restrict__ src, unsigned short* __restrict__ dst,
           const int N) {
  __shared__ unsigned short tile[32][33];
  const int k0 = blockIdx.y * 32, n0 = blockIdx.x * 32;
  const int t = threadIdx.x;
  const int r = t >> 3, c4 = (t & 7) * 4;
  const float4 v = *(const float4*)&src[(k0 + r) * N + n0 + c4];
  tile[r][c4 + 0] = f2bf(v.x);
  tile[r][c4 + 1] = f2bf(v.y);
  tile[r][c4 + 2] = f2bf(v.z);
  tile[r][c4 + 3] = f2bf(v.w);
  __syncthreads();
  ushort4 o;
  o.x = tile[c4 + 0][r];
  o.y = tile[c4 + 1][r];
  o.z = tile[c4 + 2][r];
  o.w = tile[c4 + 3][r];
  *(ushort4*)&dst[(long)(n0 + r) * 1024 + k0 + c4] = o;
}

// ---------------------------------------------------------------------------
// bf16 MFMA GEMM, m97 structure: 128x128 tile, BK=32, global_load_lds w=16,
// 4 waves, each 64x64 = 4x4 grid of 16x16x32 MFMA. K = 1024 fixed.
// A [M,1024] row-major bf16, Bt [Nn,1024] row-major bf16 (= B^T).
// MODE 0: scatter C into q/k/v (B,H,N,hd) fp32 buffers (Nn=3072).
// MODE 1: C row-major fp32 [M,1024].
// ---------------------------------------------------------------------------
template<int MODE>
__global__ __launch_bounds__(256)
void gemm_bf16(const unsigned short* __restrict__ A,
               const unsigned short* __restrict__ Bt,
               const float* __restrict__ bias, float* __restrict__ C) {
  __shared__ __align__(16) unsigned short As[128 * 32];
  __shared__ __align__(16) unsigned short Bs[128 * 32];
  const int t = threadIdx.x;
  const int bm = blockIdx.y, bn = blockIdx.x;
  const int w = t >> 6, lane = t & 63;
  const int wm = (w & 1) << 6, wn = (w >> 1) << 6;
  const int lm = lane & 15, lk = (lane >> 4) << 3;

  const unsigned short* aptr =
      A + (long)(bm * 128 + (t >> 2)) * 1024 + ((t & 3) << 3);
  const unsigned short* bptr =
      Bt + (long)(bn * 128 + (t >> 2)) * 1024 + ((t & 3) << 3);

  f32x4 acc[4][4] = {};

  for (int kk = 0; kk < 1024; kk += 32) {
    gload_lds16(aptr + kk, &As[t * 8]);
    gload_lds16(aptr + 64 * 1024 + kk, &As[2048 + t * 8]);
    gload_lds16(bptr + kk, &Bs[t * 8]);
    gload_lds16(bptr + 64 * 1024 + kk, &Bs[2048 + t * 8]);
    __syncthreads();
    bf16x8 af[4], bfr[4];
#pragma unroll
    for (int mi = 0; mi < 4; ++mi)
      af[mi] = *(const bf16x8*)&As[(wm + mi * 16 + lm) * 32 + lk];
#pragma unroll
    for (int ni = 0; ni < 4; ++ni)
      bfr[ni] = *(const bf16x8*)&Bs[(wn + ni * 16 + lm) * 32 + lk];
#pragma unroll
    for (int mi = 0; mi < 4; ++mi)
#pragma unroll
      for (int ni = 0; ni < 4; ++ni)
        acc[mi][ni] = __builtin_amdgcn_mfma_f32_16x16x32_bf16(
            af[mi], bfr[ni], acc[mi][ni], 0, 0, 0);
    __syncthreads();
  }

  // epilogue: C/D layout col=lane&15, row=(lane>>4)*4+reg
  const int r0 = (lane >> 4) << 2;
#pragma unroll
  for (int mi = 0; mi < 4; ++mi) {
#pragma unroll
    for (int ni = 0; ni < 4; ++ni) {
      const int n = bn * 128 + wn + ni * 16 + lm;
      const float bv = bias[n];
#pragma unroll
      for (int r = 0; r < 4; ++r) {
        const int m = bm * 128 + wm + mi * 16 + r0 + r;
        const float val = acc[mi][ni][r] + bv;
        if (MODE == 0) {
          const int tq = n >> 10, h = (n >> 6) & 15, d = n & 63;
          const int b = m >> 10, nn = m & 1023;
          C[tq * QSZ + (long)((b * 16 + h) * 1024 + nn) * 64 + d] = val;
        } else {
          C[(long)m * 1024 + n] = val;
        }
      }
    }
  }
}

// ---------------------------------------------------------------------------
// RMSNorm + 2D-RoPE in place on q and k, one wave per 64-elem head row.
// ---------------------------------------------------------------------------
__global__ __launch_bounds__(256)
void rmsrope_k(float* __restrict__ W, const float* __restrict__ qs,
               const float* __restrict__ ks) {
  const int t = threadIdx.x;
  const int lane = t & 63;
  const int row = blockIdx.x * 4 + (t >> 6);
  const int which = row >> 17;
  const int r = row & 131071;
  float* buf = W + which * QSZ + r * 64;
  const float* sc = which ? ks : qs;

  const float v = buf[lane];
  float ss = v * v;
#pragma unroll
  for (int off = 32; off; off >>= 1) ss += __shfl_xor(ss, off, 64);
  const float sv = v * rsqrtf(ss * (1.0f / 64.0f) + 1e-6f) * sc[lane];

  const int n = r & 1023;
  const int j = lane & 31;
  const int idx = j & 15;
  const float invf = expf(-(float)idx * 0.57564627324851149f);
  const float pos = (j < 16) ? (float)(n >> 5) : (float)(n & 31);
  const float ang = pos * invf;
  const float cs = cosf(ang), sn = sinf(ang);
  const float other = __shfl_xor(sv, 32, 64);
  const float res = (lane < 32) ? (sv * cs - other * sn)
                                : (other * sn + sv * cs);
  buf[lane] = res;
}

// ---------------------------------------------------------------------------
// Flash-style attention, fp32 vector. One block per (b,h,64-row Q tile).
// Emits O as bf16 into ob, row-major [b*1024+n, h*64+d].
// ---------------------------------------------------------------------------
__global__ __launch_bounds__(256)
void attn_k(const float* __restrict__ W, unsigned short* __restrict__ ob) {
  const float* q = W;
  const float* k = W + QSZ;
  const float* v = W + 2 * QSZ;

  __shared__ float qT[64][68];
  __shared__ float kT[64][68];
  __shared__ float vS[64][68];
  __shared__ float pT[64][68];
  __shared__ float mrow[64], lrow[64], arow_s[64];
  __shared__ float red[4][64];

  const int t = threadIdx.x;
  const int qt = blockIdx.x, bh = blockIdx.y;
  const int i0 = (t >> 4) << 2;
  const int j0 = (t & 15) << 2;
  const int seg = t >> 6, rr = t & 63;

  const float* qbase = q + (long)(bh * 1024 + qt * 64) * 64;

#pragma unroll
  for (int it = 0; it < 4; ++it) {
    const int f = it * 256 + t;
    const int row = f >> 4, c4 = (f & 15) << 2;
    const float4 g = *(const float4*)&qbase[row * 64 + c4];
    qT[c4 + 0][row] = g.x;
    qT[c4 + 1][row] = g.y;
    qT[c4 + 2][row] = g.z;
    qT[c4 + 3][row] = g.w;
  }
  if (t < 64) { mrow[t] = -INFINITY; lrow[t] = 0.0f; }
  float o_acc[4][4] = {};
  __syncthreads();

  for (int kc = 0; kc < 16; ++kc) {
    const float* kbase = k + (long)(bh * 1024 + kc * 64) * 64;
    const float* vbase = v + (long)(bh * 1024 + kc * 64) * 64;
#pragma unroll
    for (int it = 0; it < 4; ++it) {
      const int f = it * 256 + t;
      const int row = f >> 4, c4 = (f & 15) << 2;
      const float4 g = *(const float4*)&kbase[row * 64 + c4];
      kT[c4 + 0][row] = g.x;
      kT[c4 + 1][row] = g.y;
      kT[c4 + 2][row] = g.z;
      kT[c4 + 3][row] = g.w;
      *(float4*)&vS[row][c4] = *(const float4*)&vbase[row * 64 + c4];
    }
    __syncthreads();

    float s[4][4] = {};
#pragma unroll 8
    for (int d = 0; d < 64; ++d) {
      const float4 a4 = *(const float4*)&qT[d][i0];
      const float4 b4 = *(const float4*)&kT[d][j0];
      const float a[4] = {a4.x, a4.y, a4.z, a4.w};
      const float b[4] = {b4.x, b4.y, b4.z, b4.w};
#pragma unroll
      for (int ii = 0; ii < 4; ++ii)
#pragma unroll
        for (int jj = 0; jj < 4; ++jj)
          s[ii][jj] = fmaf(a[ii], b[jj], s[ii][jj]);
    }
#pragma unroll
    for (int ii = 0; ii < 4; ++ii)
#pragma unroll
      for (int jj = 0; jj < 4; ++jj)
        pT[j0 + jj][i0 + ii] = s[ii][jj] * 0.125f;
    __syncthreads();

    float cm = -INFINITY;
    for (int jj = 0; jj < 16; ++jj) cm = fmaxf(cm, pT[seg * 16 + jj][rr]);
    red[seg][rr] = cm;
    __syncthreads();

    if (t < 64) {
      const float c2 = fmaxf(fmaxf(red[0][t], red[1][t]),
                             fmaxf(red[2][t], red[3][t]));
      const float mo = mrow[t];
      const float mn = fmaxf(mo, c2);
      arow_s[t] = __expf(mo - mn);
      mrow[t] = mn;
    }
    __syncthreads();

    {
      const float mn = mrow[rr];
      float psum = 0.0f;
      for (int jj = 0; jj < 16; ++jj) {
        const int j = seg * 16 + jj;
        const float p = __expf(pT[j][rr] - mn);
        pT[j][rr] = p;
        psum += p;
      }
      red[seg][rr] = psum;
    }
    __syncthreads();

    if (t < 64)
      lrow[t] = arow_s[t] * lrow[t] +
                red[0][t] + red[1][t] + red[2][t] + red[3][t];

    float al[4];
#pragma unroll
    for (int ii = 0; ii < 4; ++ii) al[ii] = arow_s[i0 + ii];
#pragma unroll
    for (int ii = 0; ii < 4; ++ii)
#pragma unroll
      for (int dd = 0; dd < 4; ++dd) o_acc[ii][dd] *= al[ii];
#pragma unroll 8
    for (int j = 0; j < 64; ++j) {
      const float4 p4 = *(const float4*)&pT[j][i0];
      const float4 v4 = *(const float4*)&vS[j][j0];
      const float p[4] = {p4.x, p4.y, p4.z, p4.w};
      const float vv[4] = {v4.x, v4.y, v4.z, v4.w};
#pragma unroll
      for (int ii = 0; ii < 4; ++ii)
#pragma unroll
        for (int dd = 0; dd < 4; ++dd)
          o_acc[ii][dd] = fmaf(p[ii], vv[dd], o_acc[ii][dd]);
    }
    __syncthreads();
  }

  // write O as bf16, row-major [b*1024+n, h*64+d]
  const int b = bh >> 4, h = bh & 15;
#pragma unroll
  for (int ii = 0; ii < 4; ++ii) {
    const float linv = 1.0f / lrow[i0 + ii];
    ushort4 o;
    o.x = f2bf(o_acc[ii][0] * linv);
    o.y = f2bf(o_acc[ii][1] * linv);
    o.z = f2bf(o_acc[ii][2] * linv);
    o.w = f2bf(o_acc[ii][3] * linv);
    *(ushort4*)&ob[(long)(b * 1024 + qt * 64 + i0 + ii) * 1024 + h * 64 + j0] =
        o;
  }
}

extern "C" void kernel_launch(void* const* d_in, const int* in_sizes, int n_in,
                              void* d_out, int out_size, void* d_ws,
                              size_t ws_size, hipStream_t stream) {
  const float* x    = (const float*)d_in[0];
  const float* Wqkv = (const float*)d_in[1];
  const float* bqkv = (const float*)d_in[2];
  const float* Wout = (const float*)d_in[3];
  const float* bout = (const float*)d_in[4];
  const float* qs   = (const float*)d_in[5];
  const float* ks   = (const float*)d_in[6];
  float* out = (float*)d_out;
  float* W = (float*)d_ws;  // 120 MB

  unsigned short* xb  = (unsigned short*)(W + 3 * QSZ);  // 8M bf16
  unsigned short* ob  = xb;                              // reused after gemm1
  unsigned short* wqT = (unsigned short*)(W + 3 * QSZ + 4194304);  // 3M bf16
  unsigned short* woT = wqT + 3 * 1024 * 1024;                     // 1M bf16

  // prologue converts
  cvt_bf16<<<4096, 256, 0, stream>>>(x, xb);
  cvt_t<<<dim3(96, 32), 256, 0, stream>>>(Wqkv, wqT, 3072);
  cvt_t<<<dim3(32, 32), 256, 0, stream>>>(Wout, woT, 1024);
  // 1) QKV projection (bf16 MFMA), scatter into q/k/v fp32
  gemm_bf16<0><<<dim3(24, 64), 256, 0, stream>>>(xb, wqT, bqkv, W);
  // 2) RMSNorm + RoPE in place (fp32)
  rmsrope_k<<<65536, 256, 0, stream>>>(W, qs, ks);
  // 3) attention (fp32), O -> bf16 row-major ob
  attn_k<<<dim3(16, 128), 256, 0, stream>>>(W, ob);
  // 4) output projection (bf16 MFMA)
  gemm_bf16<1><<<dim3(8, 64), 256, 0, stream>>>(ob, woT, bout, out);
}

// Round 3
// 383.344 us; speedup vs baseline: 3.8858x; 2.0369x over previous
//
#include <hip/hip_runtime.h>
#include <hip/hip_bf16.h>
#include <hip/hip_fp16.h>
#include <math.h>

// B=8, H=16, N=1024, D=1024, hd=64
// ws layout (float units):
//   qpre f16 (B,H,N,64)   [0, 4M)        8M halfs
//   kpre f16 (B,H,N,64)   [4M, 8M)
//   vT   f16 (B,H,64,N)   [8M, 12M)      transposed per head
//   xb   bf16 [12M,16M)   (reused as ob after QKV gemm)
//   wqT  bf16 [16M,17.5M) ; woT bf16 [17.5M,18M)
// total 72 MB
#define QSZ 8388608  // halfs per q/k/v region

typedef short bf16x8 __attribute__((ext_vector_type(8)));
typedef _Float16 f16x8 __attribute__((ext_vector_type(8)));
typedef float f32x4 __attribute__((ext_vector_type(4)));

__device__ __forceinline__ unsigned short f2bf(float f) {
  __hip_bfloat16 h = __float2bfloat16(f);
  return *reinterpret_cast<unsigned short*>(&h);
}

__device__ __forceinline__ void gload16(const void* g, void* l) {
  __builtin_amdgcn_global_load_lds(
      (const __attribute__((address_space(1))) void*)g,
      (__attribute__((address_space(3))) void*)l, 16, 0, 0);
}

// ---------------------------------------------------------------------------
__global__ __launch_bounds__(256)
void cvt_bf16(const float* __restrict__ src, unsigned short* __restrict__ dst) {
  const int i = (blockIdx.x * 256 + threadIdx.x) * 8;
  const float4 a = *(const float4*)&src[i];
  const float4 b = *(const float4*)&src[i + 4];
  ushort4 lo, hi;
  lo.x = f2bf(a.x); lo.y = f2bf(a.y); lo.z = f2bf(a.z); lo.w = f2bf(a.w);
  hi.x = f2bf(b.x); hi.y = f2bf(b.y); hi.z = f2bf(b.z); hi.w = f2bf(b.w);
  *(ushort4*)&dst[i] = lo;
  *(ushort4*)&dst[i + 4] = hi;
}

// transpose+convert: src [1024,N] fp32 -> dst [N,1024] bf16
__global__ __launch_bounds__(256)
void cvt_t(const float* __restrict__ src, unsigned short* __restrict__ dst,
           const int N) {
  __shared__ unsigned short tile[32][33];
  const int k0 = blockIdx.y * 32, n0 = blockIdx.x * 32;
  const int t = threadIdx.x;
  const int r = t >> 3, c4 = (t & 7) * 4;
  const float4 v = *(const float4*)&src[(k0 + r) * N + n0 + c4];
  tile[r][c4 + 0] = f2bf(v.x);
  tile[r][c4 + 1] = f2bf(v.y);
  tile[r][c4 + 2] = f2bf(v.z);
  tile[r][c4 + 3] = f2bf(v.w);
  __syncthreads();
  ushort4 o;
  o.x = tile[c4 + 0][r];
  o.y = tile[c4 + 1][r];
  o.z = tile[c4 + 2][r];
  o.w = tile[c4 + 3][r];
  *(ushort4*)&dst[(long)(n0 + r) * 1024 + k0 + c4] = o;
}

// ---------------------------------------------------------------------------
// bf16 MFMA GEMM (m97 structure). MODE 0: write qkv as f16 (q/k (B,H,N,64),
// v transposed (B,H,64,N)) into Ch. MODE 1: fp32 row-major into Cf.
// ---------------------------------------------------------------------------
template<int MODE>
__global__ __launch_bounds__(256)
void gemm_bf16(const unsigned short* __restrict__ A,
               const unsigned short* __restrict__ Bt,
               const float* __restrict__ bias, float* __restrict__ Cf,
               __half* __restrict__ Ch) {
  __shared__ __align__(16) unsigned short As[128 * 32];
  __shared__ __align__(16) unsigned short Bs[128 * 32];
  const int t = threadIdx.x;
  const int bm = blockIdx.y, bn = blockIdx.x;
  const int w = t >> 6, lane = t & 63;
  const int wm = (w & 1) << 6, wn = (w >> 1) << 6;
  const int lm = lane & 15, lk = (lane >> 4) << 3;

  const unsigned short* aptr =
      A + (long)(bm * 128 + (t >> 2)) * 1024 + ((t & 3) << 3);
  const unsigned short* bptr =
      Bt + (long)(bn * 128 + (t >> 2)) * 1024 + ((t & 3) << 3);

  f32x4 acc[4][4] = {};

  for (int kk = 0; kk < 1024; kk += 32) {
    gload16(aptr + kk, &As[t * 8]);
    gload16(aptr + 64 * 1024 + kk, &As[2048 + t * 8]);
    gload16(bptr + kk, &Bs[t * 8]);
    gload16(bptr + 64 * 1024 + kk, &Bs[2048 + t * 8]);
    __syncthreads();
    bf16x8 af[4], bfr[4];
#pragma unroll
    for (int mi = 0; mi < 4; ++mi)
      af[mi] = *(const bf16x8*)&As[(wm + mi * 16 + lm) * 32 + lk];
#pragma unroll
    for (int ni = 0; ni < 4; ++ni)
      bfr[ni] = *(const bf16x8*)&Bs[(wn + ni * 16 + lm) * 32 + lk];
#pragma unroll
    for (int mi = 0; mi < 4; ++mi)
#pragma unroll
      for (int ni = 0; ni < 4; ++ni)
        acc[mi][ni] = __builtin_amdgcn_mfma_f32_16x16x32_bf16(
            af[mi], bfr[ni], acc[mi][ni], 0, 0, 0);
    __syncthreads();
  }

  const int r0 = (lane >> 4) << 2;
#pragma unroll
  for (int mi = 0; mi < 4; ++mi) {
#pragma unroll
    for (int ni = 0; ni < 4; ++ni) {
      const int n = bn * 128 + wn + ni * 16 + lm;
      const float bv = bias[n];
#pragma unroll
      for (int r = 0; r < 4; ++r) {
        const int m = bm * 128 + wm + mi * 16 + r0 + r;
        const float val = acc[mi][ni][r] + bv;
        if (MODE == 0) {
          const int tq = n >> 10, h = (n >> 6) & 15, d = n & 63;
          const int b = m >> 10, nn = m & 1023;
          long addr;
          if (tq == 2)
            addr = 2L * QSZ + ((long)((b * 16 + h) * 64 + d)) * 1024 + nn;
          else
            addr = (long)tq * QSZ + ((long)((b * 16 + h) * 1024 + nn)) * 64 + d;
          Ch[addr] = __float2half(val);
        } else {
          Cf[(long)m * 1024 + n] = val;
        }
      }
    }
  }
}

// ---------------------------------------------------------------------------
// RMSNorm + 2D-RoPE in place on f16 q/k; softmax scale 0.125 folded into q.
// ---------------------------------------------------------------------------
__global__ __launch_bounds__(256)
void rmsrope_k(__half* __restrict__ qp, __half* __restrict__ kp,
               const float* __restrict__ qs, const float* __restrict__ ks) {
  const int t = threadIdx.x, lane = t & 63;
  const int row = blockIdx.x * 4 + (t >> 6);
  const int which = row >> 17;
  const int r = row & 131071;
  __half* buf = (which ? kp : qp) + (long)r * 64;
  const float* sc = which ? ks : qs;

  const float v = __half2float(buf[lane]);
  float ss = v * v;
#pragma unroll
  for (int off = 32; off; off >>= 1) ss += __shfl_xor(ss, off, 64);
  const float sv = v * rsqrtf(ss * (1.0f / 64.0f) + 1e-6f) * sc[lane];

  const int n = r & 1023;
  const int j = lane & 31, idx = j & 15;
  const float invf = expf(-(float)idx * 0.57564627324851149f);
  const float pos = (j < 16) ? (float)(n >> 5) : (float)(n & 31);
  const float ang = pos * invf;
  const float cs = cosf(ang), sn = sinf(ang);
  const float other = __shfl_xor(sv, 32, 64);
  float res = (lane < 32) ? (sv * cs - other * sn) : (other * sn + sv * cs);
  if (!which) res *= 0.125f;  // fold hd^-0.5 into q
  buf[lane] = __float2half(res);
}

// ---------------------------------------------------------------------------
// MFMA flash attention (f16). Block = 4 waves, 64 Q-rows; wave owns 16 rows.
// K/VT chunks staged by global_load_lds with XOR chunk-swizzle in the SOURCE
// address (LDS dest stays lane-contiguous); frag reads use c^(row&7) for
// full 32-bank coverage. P transposes C->A layout via per-wave LDS strip.
// ---------------------------------------------------------------------------
__global__ __launch_bounds__(256)
void attn_mfma(const __half* __restrict__ qh, const __half* __restrict__ kh,
               const __half* __restrict__ vh, unsigned short* __restrict__ ob) {
  __shared__ __align__(16) __half Ks[4096];   // [krow][d] 64x64
  __shared__ __align__(16) __half Vs[4096];   // [d][krow] 64x64 (from vT)
  __shared__ __align__(16) __half Pl[4608];   // 4 waves x 16 x 72
  const int t = threadIdx.x;
  const int w = t >> 6, lane = t & 63;
  const int qt = blockIdx.x, bh = blockIdx.y;
  const int lm = lane & 15, q4 = lane >> 4;

  // Q A-frags in registers for the whole kernel (q pre-scaled by 0.125)
  f16x8 qf[2];
  {
    const __half* qrow =
        qh + ((long)(bh * 1024 + qt * 64 + w * 16 + lm)) * 64 + q4 * 8;
    qf[0] = *(const f16x8*)qrow;
    qf[1] = *(const f16x8*)(qrow + 32);
  }

  f32x4 o[4] = {};
  float m_r[4] = {-INFINITY, -INFINITY, -INFINITY, -INFINITY};
  float l_r[4] = {0.f, 0.f, 0.f, 0.f};

  const int prow = t >> 3, pc = t & 7;
  const int scz = pc ^ (prow & 7);  // swizzled source chunk
  const __half* ksrc0 = kh + (long)(bh * 1024 + prow) * 64 + scz * 8;
  const __half* vsrc0 = vh + (long)(bh * 64 + prow) * 1024 + scz * 8;
  __half* Pw = Pl + w * 1152;

  for (int kc = 0; kc < 16; ++kc) {
    const __half* ksrc = ksrc0 + kc * 64 * 64;
    const __half* vsrc = vsrc0 + kc * 64;
    gload16(ksrc, &Ks[t * 8]);
    gload16(ksrc + 32 * 64, &Ks[2048 + t * 8]);
    gload16(vsrc, &Vs[t * 8]);
    gload16(vsrc + 32 * 1024, &Vs[2048 + t * 8]);
    __syncthreads();

    // S = Q K^T (scale pre-folded), C layout: col=lm (krow), row=q4*4+reg
    f32x4 s[4];
#pragma unroll
    for (int nt = 0; nt < 4; ++nt) {
      s[nt] = (f32x4){0.f, 0.f, 0.f, 0.f};
      const int kr = nt * 16 + lm;
#pragma unroll
      for (int ks = 0; ks < 2; ++ks) {
        const f16x8 kf =
            *(const f16x8*)&Ks[kr * 64 + (((ks << 2) + q4) ^ (kr & 7)) * 8];
        s[nt] =
            __builtin_amdgcn_mfma_f32_16x16x32_f16(qf[ks], kf, s[nt], 0, 0, 0);
      }
    }

    // online softmax per q-row (replicated across the 16 lanes of a col group)
#pragma unroll
    for (int r = 0; r < 4; ++r) {
      float mc = fmaxf(fmaxf(s[0][r], s[1][r]), fmaxf(s[2][r], s[3][r]));
      mc = fmaxf(mc, __shfl_xor(mc, 1, 64));
      mc = fmaxf(mc, __shfl_xor(mc, 2, 64));
      mc = fmaxf(mc, __shfl_xor(mc, 4, 64));
      mc = fmaxf(mc, __shfl_xor(mc, 8, 64));
      const float mn = fmaxf(m_r[r], mc);
      const float alpha = __expf(m_r[r] - mn);
      m_r[r] = mn;
      float ps = 0.f;
#pragma unroll
      for (int nt = 0; nt < 4; ++nt) {
        const float p = __expf(s[nt][r] - mn);
        s[nt][r] = p;
        ps += p;
      }
      ps += __shfl_xor(ps, 1, 64);
      ps += __shfl_xor(ps, 2, 64);
      ps += __shfl_xor(ps, 4, 64);
      ps += __shfl_xor(ps, 8, 64);
      l_r[r] = l_r[r] * alpha + ps;
#pragma unroll
      for (int nt = 0; nt < 4; ++nt) o[nt][r] *= alpha;
      // P to LDS: C layout -> row-major [qrow][krow], stride 72
#pragma unroll
      for (int nt = 0; nt < 4; ++nt)
        Pw[(q4 * 4 + r) * 72 + nt * 16 + lm] = (__half)s[nt][r];
    }

    // O += P V ; A-frag from Pl, B-frag from Vs (vector reads)
#pragma unroll
    for (int ks2 = 0; ks2 < 2; ++ks2) {
      const f16x8 pf = *(const f16x8*)&Pw[lm * 72 + ks2 * 32 + q4 * 8];
#pragma unroll
      for (int nt = 0; nt < 4; ++nt) {
        const int dr = nt * 16 + lm;
        const f16x8 vf =
            *(const f16x8*)&Vs[dr * 64 + (((ks2 << 2) + q4) ^ (dr & 7)) * 8];
        o[nt] = __builtin_amdgcn_mfma_f32_16x16x32_f16(pf, vf, o[nt], 0, 0, 0);
      }
    }
    __syncthreads();
  }

  // normalize, write O bf16 row-major [b*1024+n][h*64+d]
  const int b = bh >> 4, h = bh & 15;
#pragma unroll
  for (int r = 0; r < 4; ++r) {
    const float linv = 1.0f / l_r[r];
    const long rowg =
        (long)(b * 1024 + qt * 64 + w * 16 + q4 * 4 + r) * 1024 + h * 64;
#pragma unroll
    for (int nt = 0; nt < 4; ++nt)
      ob[rowg + nt * 16 + lm] = f2bf(o[nt][r] * linv);
  }
}

extern "C" void kernel_launch(void* const* d_in, const int* in_sizes, int n_in,
                              void* d_out, int out_size, void* d_ws,
                              size_t ws_size, hipStream_t stream) {
  const float* x    = (const float*)d_in[0];
  const float* Wqkv = (const float*)d_in[1];
  const float* bqkv = (const float*)d_in[2];
  const float* Wout = (const float*)d_in[3];
  const float* bout = (const float*)d_in[4];
  const float* qs   = (const float*)d_in[5];
  const float* ks   = (const float*)d_in[6];
  float* out = (float*)d_out;
  float* W = (float*)d_ws;  // 72 MB

  __half* qkvh = (__half*)W;            // q:0  k:+QSZ  vT:+2*QSZ (halfs)
  __half* qpre = qkvh;
  __half* kpre = qkvh + QSZ;
  __half* vT   = qkvh + 2 * QSZ;
  unsigned short* xb  = (unsigned short*)(W + 12582912);
  unsigned short* ob  = xb;
  unsigned short* wqT = (unsigned short*)(W + 16777216);
  unsigned short* woT = wqT + 3 * 1024 * 1024;

  cvt_bf16<<<4096, 256, 0, stream>>>(x, xb);
  cvt_t<<<dim3(96, 32), 256, 0, stream>>>(Wqkv, wqT, 3072);
  cvt_t<<<dim3(32, 32), 256, 0, stream>>>(Wout, woT, 1024);
  // 1) QKV projection -> q/k f16 (B,H,N,64), v f16 transposed (B,H,64,N)
  gemm_bf16<0><<<dim3(24, 64), 256, 0, stream>>>(xb, wqT, bqkv, nullptr, qkvh);
  // 2) RMSNorm + RoPE in place (q scaled by 0.125)
  rmsrope_k<<<65536, 256, 0, stream>>>(qpre, kpre, qs, ks);
  // 3) MFMA flash attention -> ob bf16 row-major
  attn_mfma<<<dim3(16, 128), 256, 0, stream>>>(qpre, kpre, vT, ob);
  // 4) output projection
  gemm_bf16<1><<<dim3(8, 64), 256, 0, stream>>>(ob, woT, bout, out, nullptr);
}

// Round 4
// 344.446 us; speedup vs baseline: 4.3247x; 1.1129x over previous
//
#include <hip/hip_runtime.h>
#include <hip/hip_bf16.h>
#include <hip/hip_fp16.h>
#include <math.h>

// B=8, H=16, N=1024, D=1024, hd=64
// ws layout (float units):
//   qpre f16 (B,H,N,64)   [0, 4M)        8M halfs
//   kpre f16 (B,H,N,64)   [4M, 8M)
//   vT   f16 (B,H,64,N)   [8M, 12M)      transposed per head
//   xb   bf16 [12M,16M)   (reused as ob after QKV gemm)
//   wqT  bf16 [16M,17.5M) ; woT bf16 [17.5M,18M)
// total 72 MB
#define QSZ 8388608  // halfs per q/k/v region

typedef short bf16x8 __attribute__((ext_vector_type(8)));
typedef _Float16 f16x8 __attribute__((ext_vector_type(8)));
typedef float f32x4 __attribute__((ext_vector_type(4)));

__device__ __forceinline__ unsigned short f2bf(float f) {
  __hip_bfloat16 h = __float2bfloat16(f);
  return *reinterpret_cast<unsigned short*>(&h);
}

__device__ __forceinline__ void gload16(const void* g, void* l) {
  __builtin_amdgcn_global_load_lds(
      (const __attribute__((address_space(1))) void*)g,
      (__attribute__((address_space(3))) void*)l, 16, 0, 0);
}

// ---------------------------------------------------------------------------
__global__ __launch_bounds__(256)
void cvt_bf16(const float* __restrict__ src, unsigned short* __restrict__ dst) {
  const int i = (blockIdx.x * 256 + threadIdx.x) * 8;
  const float4 a = *(const float4*)&src[i];
  const float4 b = *(const float4*)&src[i + 4];
  ushort4 lo, hi;
  lo.x = f2bf(a.x); lo.y = f2bf(a.y); lo.z = f2bf(a.z); lo.w = f2bf(a.w);
  hi.x = f2bf(b.x); hi.y = f2bf(b.y); hi.z = f2bf(b.z); hi.w = f2bf(b.w);
  *(ushort4*)&dst[i] = lo;
  *(ushort4*)&dst[i + 4] = hi;
}

// transpose+convert: src [1024,N] fp32 -> dst [N,1024] bf16
__global__ __launch_bounds__(256)
void cvt_t(const float* __restrict__ src, unsigned short* __restrict__ dst,
           const int N) {
  __shared__ unsigned short tile[32][33];
  const int k0 = blockIdx.y * 32, n0 = blockIdx.x * 32;
  const int t = threadIdx.x;
  const int r = t >> 3, c4 = (t & 7) * 4;
  const float4 v = *(const float4*)&src[(k0 + r) * N + n0 + c4];
  tile[r][c4 + 0] = f2bf(v.x);
  tile[r][c4 + 1] = f2bf(v.y);
  tile[r][c4 + 2] = f2bf(v.z);
  tile[r][c4 + 3] = f2bf(v.w);
  __syncthreads();
  ushort4 o;
  o.x = tile[c4 + 0][r];
  o.y = tile[c4 + 1][r];
  o.z = tile[c4 + 2][r];
  o.w = tile[c4 + 3][r];
  *(ushort4*)&dst[(long)(n0 + r) * 1024 + k0 + c4] = o;
}

// ---------------------------------------------------------------------------
// bf16 MFMA GEMM (m97 structure). MODE 0: write qkv as f16 (q/k (B,H,N,64),
// v transposed (B,H,64,N)) into Ch. MODE 1: fp32 row-major into Cf.
// ---------------------------------------------------------------------------
template<int MODE>
__global__ __launch_bounds__(256)
void gemm_bf16(const unsigned short* __restrict__ A,
               const unsigned short* __restrict__ Bt,
               const float* __restrict__ bias, float* __restrict__ Cf,
               __half* __restrict__ Ch) {
  __shared__ __align__(16) unsigned short As[128 * 32];
  __shared__ __align__(16) unsigned short Bs[128 * 32];
  const int t = threadIdx.x;
  const int bm = blockIdx.y, bn = blockIdx.x;
  const int w = t >> 6, lane = t & 63;
  const int wm = (w & 1) << 6, wn = (w >> 1) << 6;
  const int lm = lane & 15, lk = (lane >> 4) << 3;

  const unsigned short* aptr =
      A + (long)(bm * 128 + (t >> 2)) * 1024 + ((t & 3) << 3);
  const unsigned short* bptr =
      Bt + (long)(bn * 128 + (t >> 2)) * 1024 + ((t & 3) << 3);

  f32x4 acc[4][4] = {};

  for (int kk = 0; kk < 1024; kk += 32) {
    gload16(aptr + kk, &As[t * 8]);
    gload16(aptr + 64 * 1024 + kk, &As[2048 + t * 8]);
    gload16(bptr + kk, &Bs[t * 8]);
    gload16(bptr + 64 * 1024 + kk, &Bs[2048 + t * 8]);
    __syncthreads();
    bf16x8 af[4], bfr[4];
#pragma unroll
    for (int mi = 0; mi < 4; ++mi)
      af[mi] = *(const bf16x8*)&As[(wm + mi * 16 + lm) * 32 + lk];
#pragma unroll
    for (int ni = 0; ni < 4; ++ni)
      bfr[ni] = *(const bf16x8*)&Bs[(wn + ni * 16 + lm) * 32 + lk];
#pragma unroll
    for (int mi = 0; mi < 4; ++mi)
#pragma unroll
      for (int ni = 0; ni < 4; ++ni)
        acc[mi][ni] = __builtin_amdgcn_mfma_f32_16x16x32_bf16(
            af[mi], bfr[ni], acc[mi][ni], 0, 0, 0);
    __syncthreads();
  }

  const int r0 = (lane >> 4) << 2;
#pragma unroll
  for (int mi = 0; mi < 4; ++mi) {
#pragma unroll
    for (int ni = 0; ni < 4; ++ni) {
      const int n = bn * 128 + wn + ni * 16 + lm;
      const float bv = bias[n];
#pragma unroll
      for (int r = 0; r < 4; ++r) {
        const int m = bm * 128 + wm + mi * 16 + r0 + r;
        const float val = acc[mi][ni][r] + bv;
        if (MODE == 0) {
          const int tq = n >> 10, h = (n >> 6) & 15, d = n & 63;
          const int b = m >> 10, nn = m & 1023;
          long addr;
          if (tq == 2)
            addr = 2L * QSZ + ((long)((b * 16 + h) * 64 + d)) * 1024 + nn;
          else
            addr = (long)tq * QSZ + ((long)((b * 16 + h) * 1024 + nn)) * 64 + d;
          Ch[addr] = __float2half(val);
        } else {
          Cf[(long)m * 1024 + n] = val;
        }
      }
    }
  }
}

// ---------------------------------------------------------------------------
// RMSNorm + 2D-RoPE in place on f16 q/k; softmax scale 0.125 folded into q.
// ---------------------------------------------------------------------------
__global__ __launch_bounds__(256)
void rmsrope_k(__half* __restrict__ qp, __half* __restrict__ kp,
               const float* __restrict__ qs, const float* __restrict__ ks) {
  const int t = threadIdx.x, lane = t & 63;
  const int row = blockIdx.x * 4 + (t >> 6);
  const int which = row >> 17;
  const int r = row & 131071;
  __half* buf = (which ? kp : qp) + (long)r * 64;
  const float* sc = which ? ks : qs;

  const float v = __half2float(buf[lane]);
  float ss = v * v;
#pragma unroll
  for (int off = 32; off; off >>= 1) ss += __shfl_xor(ss, off, 64);
  const float sv = v * rsqrtf(ss * (1.0f / 64.0f) + 1e-6f) * sc[lane];

  const int n = r & 1023;
  const int j = lane & 31, idx = j & 15;
  const float invf = expf(-(float)idx * 0.57564627324851149f);
  const float pos = (j < 16) ? (float)(n >> 5) : (float)(n & 31);
  const float ang = pos * invf;
  const float cs = cosf(ang), sn = sinf(ang);
  const float other = __shfl_xor(sv, 32, 64);
  float res = (lane < 32) ? (sv * cs - other * sn) : (other * sn + sv * cs);
  if (!which) res *= 0.125f;  // fold hd^-0.5 into q
  buf[lane] = __float2half(res);
}

// ---------------------------------------------------------------------------
// MFMA flash attention (f16), fixed-offset softmax + double-buffered staging.
// Block = 4 waves, 64 Q-rows; wave owns 16 rows (Q frags in registers).
// After RMSNorm: ||q||=1 (0.125 folded), ||k||=8 -> s = q.k <= 8 always.
// p = exp(s - 9): no running max, no O-rescale, no in-loop cross-lane ops.
// l accumulated per-lane, reduced once at the end.
// K/V chunk kc+1 is prefetched via global_load_lds into the alternate buffer
// while chunk kc computes -> the barrier's vmcnt drain is ~free.
// ---------------------------------------------------------------------------
__global__ __launch_bounds__(256)
void attn_mfma(const __half* __restrict__ qh, const __half* __restrict__ kh,
               const __half* __restrict__ vh, unsigned short* __restrict__ ob) {
  __shared__ __align__(16) __half Ks[2][4096];  // [krow][d] 64x64, swizzled
  __shared__ __align__(16) __half Vs[2][4096];  // [d][krow] 64x64, swizzled
  __shared__ __align__(16) __half Pl[4608];     // 4 waves x 16 x 72
  const int t = threadIdx.x;
  const int w = t >> 6, lane = t & 63;
  const int qt = blockIdx.x, bh = blockIdx.y;
  const int lm = lane & 15, q4 = lane >> 4;

  // Q A-frags in registers for the whole kernel (q pre-scaled by 0.125)
  f16x8 qf[2];
  {
    const __half* qrow =
        qh + ((long)(bh * 1024 + qt * 64 + w * 16 + lm)) * 64 + q4 * 8;
    qf[0] = *(const f16x8*)qrow;
    qf[1] = *(const f16x8*)(qrow + 32);
  }

  f32x4 o[4] = {};
  float l_r[4] = {0.f, 0.f, 0.f, 0.f};

  const int prow = t >> 3, pc = t & 7;
  const int scz = pc ^ (prow & 7);  // swizzled source chunk
  const __half* ksrc0 = kh + (long)(bh * 1024 + prow) * 64 + scz * 8;
  const __half* vsrc0 = vh + (long)(bh * 64 + prow) * 1024 + scz * 8;
  __half* Pw = Pl + w * 1152;

  // prologue: stage chunk 0 into buffer 0
  gload16(ksrc0, &Ks[0][t * 8]);
  gload16(ksrc0 + 32 * 64, &Ks[0][2048 + t * 8]);
  gload16(vsrc0, &Vs[0][t * 8]);
  gload16(vsrc0 + 32 * 1024, &Vs[0][2048 + t * 8]);

  for (int kc = 0; kc < 16; ++kc) {
    const int cur = kc & 1;
    __syncthreads();  // chunk kc staged; all waves done with buffer cur^1

    if (kc < 15) {  // prefetch chunk kc+1 into the other buffer
      const int nx = cur ^ 1;
      const __half* ksrc = ksrc0 + (kc + 1) * 4096;
      const __half* vsrc = vsrc0 + (kc + 1) * 64;
      gload16(ksrc, &Ks[nx][t * 8]);
      gload16(ksrc + 32 * 64, &Ks[nx][2048 + t * 8]);
      gload16(vsrc, &Vs[nx][t * 8]);
      gload16(vsrc + 32 * 1024, &Vs[nx][2048 + t * 8]);
    }

    // S = Q K^T (scale pre-folded), C layout: col=lm (krow), row=q4*4+reg
    f32x4 s[4];
#pragma unroll
    for (int nt = 0; nt < 4; ++nt) {
      s[nt] = (f32x4){0.f, 0.f, 0.f, 0.f};
      const int kr = nt * 16 + lm;
#pragma unroll
      for (int ks = 0; ks < 2; ++ks) {
        const f16x8 kf = *(const f16x8*)&Ks[cur][kr * 64 +
                                              (((ks << 2) + q4) ^ (kr & 7)) * 8];
        s[nt] =
            __builtin_amdgcn_mfma_f32_16x16x32_f16(qf[ks], kf, s[nt], 0, 0, 0);
      }
    }

    // fixed-offset softmax: p = exp(s-9), per-lane l partials, P -> LDS
#pragma unroll
    for (int nt = 0; nt < 4; ++nt) {
#pragma unroll
      for (int r = 0; r < 4; ++r) {
        const float p = __expf(s[nt][r] - 9.0f);
        l_r[r] += p;
        Pw[(q4 * 4 + r) * 72 + nt * 16 + lm] = (__half)p;
      }
    }

    // O += P V ; A-frag from Pl, B-frag from Vs (vector reads)
#pragma unroll
    for (int ks2 = 0; ks2 < 2; ++ks2) {
      const f16x8 pf = *(const f16x8*)&Pw[lm * 72 + ks2 * 32 + q4 * 8];
#pragma unroll
      for (int nt = 0; nt < 4; ++nt) {
        const int dr = nt * 16 + lm;
        const f16x8 vf = *(const f16x8*)&Vs[cur][dr * 64 +
                                               (((ks2 << 2) + q4) ^ (dr & 7)) * 8];
        o[nt] = __builtin_amdgcn_mfma_f32_16x16x32_f16(pf, vf, o[nt], 0, 0, 0);
      }
    }
    __syncthreads();  // all waves done with buffer cur before restaging it
  }

  // final l reduction across the 16 lanes (lm bits) holding each q-row
  float linv[4];
#pragma unroll
  for (int r = 0; r < 4; ++r) {
    float l = l_r[r];
    l += __shfl_xor(l, 1, 64);
    l += __shfl_xor(l, 2, 64);
    l += __shfl_xor(l, 4, 64);
    l += __shfl_xor(l, 8, 64);
    linv[r] = 1.0f / l;
  }

  // normalize, write O bf16 row-major [b*1024+n][h*64+d]
  const int b = bh >> 4, h = bh & 15;
#pragma unroll
  for (int r = 0; r < 4; ++r) {
    const long rowg =
        (long)(b * 1024 + qt * 64 + w * 16 + q4 * 4 + r) * 1024 + h * 64;
#pragma unroll
    for (int nt = 0; nt < 4; ++nt)
      ob[rowg + nt * 16 + lm] = f2bf(o[nt][r] * linv[r]);
  }
}

extern "C" void kernel_launch(void* const* d_in, const int* in_sizes, int n_in,
                              void* d_out, int out_size, void* d_ws,
                              size_t ws_size, hipStream_t stream) {
  const float* x    = (const float*)d_in[0];
  const float* Wqkv = (const float*)d_in[1];
  const float* bqkv = (const float*)d_in[2];
  const float* Wout = (const float*)d_in[3];
  const float* bout = (const float*)d_in[4];
  const float* qs   = (const float*)d_in[5];
  const float* ks   = (const float*)d_in[6];
  float* out = (float*)d_out;
  float* W = (float*)d_ws;  // 72 MB

  __half* qkvh = (__half*)W;            // q:0  k:+QSZ  vT:+2*QSZ (halfs)
  __half* qpre = qkvh;
  __half* kpre = qkvh + QSZ;
  __half* vT   = qkvh + 2 * QSZ;
  unsigned short* xb  = (unsigned short*)(W + 12582912);
  unsigned short* ob  = xb;
  unsigned short* wqT = (unsigned short*)(W + 16777216);
  unsigned short* woT = wqT + 3 * 1024 * 1024;

  cvt_bf16<<<4096, 256, 0, stream>>>(x, xb);
  cvt_t<<<dim3(96, 32), 256, 0, stream>>>(Wqkv, wqT, 3072);
  cvt_t<<<dim3(32, 32), 256, 0, stream>>>(Wout, woT, 1024);
  // 1) QKV projection -> q/k f16 (B,H,N,64), v f16 transposed (B,H,64,N)
  gemm_bf16<0><<<dim3(24, 64), 256, 0, stream>>>(xb, wqT, bqkv, nullptr, qkvh);
  // 2) RMSNorm + RoPE in place (q scaled by 0.125)
  rmsrope_k<<<65536, 256, 0, stream>>>(qpre, kpre, qs, ks);
  // 3) MFMA flash attention -> ob bf16 row-major
  attn_mfma<<<dim3(16, 128), 256, 0, stream>>>(qpre, kpre, vT, ob);
  // 4) output projection
  gemm_bf16<1><<<dim3(8, 64), 256, 0, stream>>>(ob, woT, bout, out, nullptr);
}

// Round 5
// 308.540 us; speedup vs baseline: 4.8279x; 1.1164x over previous
//
#include <hip/hip_runtime.h>
#include <hip/hip_bf16.h>
#include <hip/hip_fp16.h>
#include <math.h>

// B=8, H=16, N=1024, D=1024, hd=64
// ws layout (float units):
//   qpre f16 (B,H,N,64)   [0, 4M)        8M halfs   (normed+roped by gemm)
//   kpre f16 (B,H,N,64)   [4M, 8M)
//   vT   f16 (B,H,64,N)   [8M, 12M)      transposed per head
//   xb   bf16 [12M,16M)   (reused as ob after QKV gemm)
//   wqT  bf16 [16M,17.5M) ; woT bf16 [17.5M,18M)
// total 72 MB
#define QSZ 8388608  // halfs per q/k/v region

typedef short bf16x8 __attribute__((ext_vector_type(8)));
typedef _Float16 f16x8 __attribute__((ext_vector_type(8)));
typedef float f32x4 __attribute__((ext_vector_type(4)));

__device__ __forceinline__ unsigned short f2bf(float f) {
  __hip_bfloat16 h = __float2bfloat16(f);
  return *reinterpret_cast<unsigned short*>(&h);
}

__device__ __forceinline__ void gload16(const void* g, void* l) {
  __builtin_amdgcn_global_load_lds(
      (const __attribute__((address_space(1))) void*)g,
      (__attribute__((address_space(3))) void*)l, 16, 0, 0);
}

// ---------------------------------------------------------------------------
__global__ __launch_bounds__(256)
void cvt_bf16(const float* __restrict__ src, unsigned short* __restrict__ dst) {
  const int i = (blockIdx.x * 256 + threadIdx.x) * 8;
  const float4 a = *(const float4*)&src[i];
  const float4 b = *(const float4*)&src[i + 4];
  ushort4 lo, hi;
  lo.x = f2bf(a.x); lo.y = f2bf(a.y); lo.z = f2bf(a.z); lo.w = f2bf(a.w);
  hi.x = f2bf(b.x); hi.y = f2bf(b.y); hi.z = f2bf(b.z); hi.w = f2bf(b.w);
  *(ushort4*)&dst[i] = lo;
  *(ushort4*)&dst[i + 4] = hi;
}

// transpose+convert: src [1024,N] fp32 -> dst [N,1024] bf16
__global__ __launch_bounds__(256)
void cvt_t(const float* __restrict__ src, unsigned short* __restrict__ dst,
           const int N) {
  __shared__ unsigned short tile[32][33];
  const int k0 = blockIdx.y * 32, n0 = blockIdx.x * 32;
  const int t = threadIdx.x;
  const int r = t >> 3, c4 = (t & 7) * 4;
  const float4 v = *(const float4*)&src[(k0 + r) * N + n0 + c4];
  tile[r][c4 + 0] = f2bf(v.x);
  tile[r][c4 + 1] = f2bf(v.y);
  tile[r][c4 + 2] = f2bf(v.z);
  tile[r][c4 + 3] = f2bf(v.w);
  __syncthreads();
  ushort4 o;
  o.x = tile[c4 + 0][r];
  o.y = tile[c4 + 1][r];
  o.z = tile[c4 + 2][r];
  o.w = tile[c4 + 3][r];
  *(ushort4*)&dst[(long)(n0 + r) * 1024 + k0 + c4] = o;
}

// ---------------------------------------------------------------------------
// bf16 MFMA GEMM, single-barrier double-buffered staging.
// MODE 0 (QKV): fused epilogue does RMSNorm + 2D-RoPE (+0.125 fold into q) on
//   the f32 accumulators and writes q/k f16 (B,H,N,64), v f16 transposed
//   (B,H,64,N). A wave's 64-col span = one (tq,head); d = ni*16+lm; the RoPE
//   pair (d,d+32) = (ni,ni+2) is lane-local; sum-of-squares = 4 shfl_xor.
// MODE 1 (out-proj): fp32 row-major into Cf.
// ---------------------------------------------------------------------------
template<int MODE>
__global__ __launch_bounds__(256)
void gemm_bf16(const unsigned short* __restrict__ A,
               const unsigned short* __restrict__ Bt,
               const float* __restrict__ bias, float* __restrict__ Cf,
               __half* __restrict__ Ch, const float* __restrict__ qsc,
               const float* __restrict__ ksc) {
  __shared__ __align__(16) unsigned short As[2][4096];
  __shared__ __align__(16) unsigned short Bs[2][4096];
  __shared__ float2 Tab[512];  // [pos 0..31][idx 0..15] cos/sin
  const int t = threadIdx.x;
  const int bm = blockIdx.y, bn = blockIdx.x;
  const int w = t >> 6, lane = t & 63;
  const int wm = (w & 1) << 6, wn = (w >> 1) << 6;
  const int lm = lane & 15, lk = (lane >> 4) << 3;

  if (MODE == 0) {  // build RoPE table (visible after first barrier)
    for (int e = t; e < 512; e += 256) {
      const int pos = e >> 4, idx = e & 15;
      const float invf = expf(-(float)idx * 0.57564627324851149f);
      const float ang = (float)pos * invf;
      Tab[e] = make_float2(cosf(ang), sinf(ang));
    }
  }

  const unsigned short* aptr =
      A + (long)(bm * 128 + (t >> 2)) * 1024 + ((t & 3) << 3);
  const unsigned short* bptr =
      Bt + (long)(bn * 128 + (t >> 2)) * 1024 + ((t & 3) << 3);

  f32x4 acc[4][4] = {};

  // prologue: stage k-tile 0 into buffer 0
  gload16(aptr, &As[0][t * 8]);
  gload16(aptr + 64 * 1024, &As[0][2048 + t * 8]);
  gload16(bptr, &Bs[0][t * 8]);
  gload16(bptr + 64 * 1024, &Bs[0][2048 + t * 8]);

  for (int it = 0; it < 32; ++it) {
    const int cur = it & 1;
    __syncthreads();  // drains this wave's vmcnt -> tile `it` staged for all
    if (it < 31) {    // prefetch tile it+1 into the other buffer
      const int nx = cur ^ 1;
      const int kk = (it + 1) * 32;
      gload16(aptr + kk, &As[nx][t * 8]);
      gload16(aptr + 64 * 1024 + kk, &As[nx][2048 + t * 8]);
      gload16(bptr + kk, &Bs[nx][t * 8]);
      gload16(bptr + 64 * 1024 + kk, &Bs[nx][2048 + t * 8]);
    }
    bf16x8 af[4], bfr[4];
#pragma unroll
    for (int mi = 0; mi < 4; ++mi)
      af[mi] = *(const bf16x8*)&As[cur][(wm + mi * 16 + lm) * 32 + lk];
#pragma unroll
    for (int ni = 0; ni < 4; ++ni)
      bfr[ni] = *(const bf16x8*)&Bs[cur][(wn + ni * 16 + lm) * 32 + lk];
#pragma unroll
    for (int mi = 0; mi < 4; ++mi)
#pragma unroll
      for (int ni = 0; ni < 4; ++ni)
        acc[mi][ni] = __builtin_amdgcn_mfma_f32_16x16x32_bf16(
            af[mi], bfr[ni], acc[mi][ni], 0, 0, 0);
  }

  const int r0 = (lane >> 4) << 2;  // q4*4
  const int nb = bn * 128 + wn;     // wave's col base

  if (MODE == 1) {
#pragma unroll
    for (int mi = 0; mi < 4; ++mi)
#pragma unroll
      for (int ni = 0; ni < 4; ++ni) {
        const int n = nb + ni * 16 + lm;
        const float bv = bias[n];
#pragma unroll
        for (int r = 0; r < 4; ++r)
          Cf[(long)(bm * 128 + wm + mi * 16 + r0 + r) * 1024 + n] =
              acc[mi][ni][r] + bv;
      }
    return;
  }

  // ---- MODE 0 fused epilogue ----
  const int tq = nb >> 10, h = (nb >> 6) & 15;
  if (tq == 2) {  // v: plain f16 transpose-scatter (B,H,64,N)
#pragma unroll
    for (int mi = 0; mi < 4; ++mi)
#pragma unroll
      for (int ni = 0; ni < 4; ++ni) {
        const int d = (nb & 1023) + ni * 16 + lm - 1024 * 2 + 2048;  // d in head
        const int dd = ((nb + ni * 16 + lm) & 63);
        const float bv = bias[nb + ni * 16 + lm];
#pragma unroll
        for (int r = 0; r < 4; ++r) {
          const int m = bm * 128 + wm + mi * 16 + r0 + r;
          const int b = m >> 10, nn = m & 1023;
          Ch[2L * QSZ + ((long)((b * 16 + h) * 64 + dd)) * 1024 + nn] =
              __float2half(acc[mi][ni][r] + bv);
        }
      }
    return;
  }

  // q or k: RMSNorm + RoPE on f32 accs, then f16 store (B,H,N,64)
  const float* scp = (tq == 0) ? qsc : ksc;
  const float qmul = (tq == 0) ? 0.125f : 1.0f;  // fold hd^-0.5 into q
  float scv[4], bv[4];
#pragma unroll
  for (int ni = 0; ni < 4; ++ni) {
    scv[ni] = scp[ni * 16 + lm];
    bv[ni] = bias[nb + ni * 16 + lm];
  }
  __half* base = Ch + (long)tq * QSZ;
#pragma unroll
  for (int mi = 0; mi < 4; ++mi) {
#pragma unroll
    for (int r = 0; r < 4; ++r) {
      const float v0 = acc[mi][0][r] + bv[0];
      const float v1 = acc[mi][1][r] + bv[1];
      const float v2 = acc[mi][2][r] + bv[2];
      const float v3 = acc[mi][3][r] + bv[3];
      float ss = v0 * v0 + v1 * v1 + v2 * v2 + v3 * v3;
      ss += __shfl_xor(ss, 1, 64);
      ss += __shfl_xor(ss, 2, 64);
      ss += __shfl_xor(ss, 4, 64);
      ss += __shfl_xor(ss, 8, 64);
      const float inv = rsqrtf(ss * (1.0f / 64.0f) + 1e-6f) * qmul;
      const float a0 = v0 * inv * scv[0];
      const float a1 = v1 * inv * scv[1];
      const float a2 = v2 * inv * scv[2];
      const float a3 = v3 * inv * scv[3];
      const int m = bm * 128 + wm + mi * 16 + r0 + r;
      const int b = m >> 10, nn = m & 1023;
      const float2 tr = Tab[(nn >> 5) * 16 + lm];  // row-part angles
      const float2 tc = Tab[(nn & 31) * 16 + lm];  // col-part angles
      __half* row = base + ((long)((b * 16 + h) * 1024 + nn)) * 64 + lm;
      row[0]  = __float2half(a0 * tr.x - a2 * tr.y);
      row[16] = __float2half(a1 * tc.x - a3 * tc.y);
      row[32] = __float2half(a0 * tr.y + a2 * tr.x);
      row[48] = __float2half(a1 * tc.y + a3 * tc.x);
    }
  }
}

// ---------------------------------------------------------------------------
// MFMA flash attention (f16), fixed-offset softmax, single-barrier dbuf.
// ||q||=1 (0.125 folded), ||k||=8 -> s <= 8; p = exp(s-9).
// ---------------------------------------------------------------------------
__global__ __launch_bounds__(256)
void attn_mfma(const __half* __restrict__ qh, const __half* __restrict__ kh,
               const __half* __restrict__ vh, unsigned short* __restrict__ ob) {
  __shared__ __align__(16) __half Ks[2][4096];  // [krow][d] 64x64, swizzled
  __shared__ __align__(16) __half Vs[2][4096];  // [d][krow] 64x64, swizzled
  __shared__ __align__(16) __half Pl[4608];     // 4 waves x 16 x 72
  const int t = threadIdx.x;
  const int w = t >> 6, lane = t & 63;
  const int qt = blockIdx.x, bh = blockIdx.y;
  const int lm = lane & 15, q4 = lane >> 4;

  f16x8 qf[2];
  {
    const __half* qrow =
        qh + ((long)(bh * 1024 + qt * 64 + w * 16 + lm)) * 64 + q4 * 8;
    qf[0] = *(const f16x8*)qrow;
    qf[1] = *(const f16x8*)(qrow + 32);
  }

  f32x4 o[4] = {};
  float l_r[4] = {0.f, 0.f, 0.f, 0.f};

  const int prow = t >> 3, pc = t & 7;
  const int scz = pc ^ (prow & 7);  // swizzled source chunk
  const __half* ksrc0 = kh + (long)(bh * 1024 + prow) * 64 + scz * 8;
  const __half* vsrc0 = vh + (long)(bh * 64 + prow) * 1024 + scz * 8;
  __half* Pw = Pl + w * 1152;

  gload16(ksrc0, &Ks[0][t * 8]);
  gload16(ksrc0 + 32 * 64, &Ks[0][2048 + t * 8]);
  gload16(vsrc0, &Vs[0][t * 8]);
  gload16(vsrc0 + 32 * 1024, &Vs[0][2048 + t * 8]);

  for (int kc = 0; kc < 16; ++kc) {
    const int cur = kc & 1;
    __syncthreads();  // chunk kc staged for all waves

    if (kc < 15) {
      const int nx = cur ^ 1;
      const __half* ksrc = ksrc0 + (kc + 1) * 4096;
      const __half* vsrc = vsrc0 + (kc + 1) * 64;
      gload16(ksrc, &Ks[nx][t * 8]);
      gload16(ksrc + 32 * 64, &Ks[nx][2048 + t * 8]);
      gload16(vsrc, &Vs[nx][t * 8]);
      gload16(vsrc + 32 * 1024, &Vs[nx][2048 + t * 8]);
    }

    f32x4 s[4];
#pragma unroll
    for (int nt = 0; nt < 4; ++nt) {
      s[nt] = (f32x4){0.f, 0.f, 0.f, 0.f};
      const int kr = nt * 16 + lm;
#pragma unroll
      for (int ks = 0; ks < 2; ++ks) {
        const f16x8 kf = *(const f16x8*)&Ks[cur][kr * 64 +
                                              (((ks << 2) + q4) ^ (kr & 7)) * 8];
        s[nt] =
            __builtin_amdgcn_mfma_f32_16x16x32_f16(qf[ks], kf, s[nt], 0, 0, 0);
      }
    }

#pragma unroll
    for (int nt = 0; nt < 4; ++nt) {
#pragma unroll
      for (int r = 0; r < 4; ++r) {
        const float p = __expf(s[nt][r] - 9.0f);
        l_r[r] += p;
        Pw[(q4 * 4 + r) * 72 + nt * 16 + lm] = (__half)p;
      }
    }

#pragma unroll
    for (int ks2 = 0; ks2 < 2; ++ks2) {
      const f16x8 pf = *(const f16x8*)&Pw[lm * 72 + ks2 * 32 + q4 * 8];
#pragma unroll
      for (int nt = 0; nt < 4; ++nt) {
        const int dr = nt * 16 + lm;
        const f16x8 vf = *(const f16x8*)&Vs[cur][dr * 64 +
                                               (((ks2 << 2) + q4) ^ (dr & 7)) * 8];
        o[nt] = __builtin_amdgcn_mfma_f32_16x16x32_f16(pf, vf, o[nt], 0, 0, 0);
      }
    }
  }

  float linv[4];
#pragma unroll
  for (int r = 0; r < 4; ++r) {
    float l = l_r[r];
    l += __shfl_xor(l, 1, 64);
    l += __shfl_xor(l, 2, 64);
    l += __shfl_xor(l, 4, 64);
    l += __shfl_xor(l, 8, 64);
    linv[r] = 1.0f / l;
  }

  const int b = bh >> 4, h = bh & 15;
#pragma unroll
  for (int r = 0; r < 4; ++r) {
    const long rowg =
        (long)(b * 1024 + qt * 64 + w * 16 + q4 * 4 + r) * 1024 + h * 64;
#pragma unroll
    for (int nt = 0; nt < 4; ++nt)
      ob[rowg + nt * 16 + lm] = f2bf(o[nt][r] * linv[r]);
  }
}

extern "C" void kernel_launch(void* const* d_in, const int* in_sizes, int n_in,
                              void* d_out, int out_size, void* d_ws,
                              size_t ws_size, hipStream_t stream) {
  const float* x    = (const float*)d_in[0];
  const float* Wqkv = (const float*)d_in[1];
  const float* bqkv = (const float*)d_in[2];
  const float* Wout = (const float*)d_in[3];
  const float* bout = (const float*)d_in[4];
  const float* qs   = (const float*)d_in[5];
  const float* ks   = (const float*)d_in[6];
  float* out = (float*)d_out;
  float* W = (float*)d_ws;  // 72 MB

  __half* qkvh = (__half*)W;            // q:0  k:+QSZ  vT:+2*QSZ (halfs)
  __half* qpre = qkvh;
  __half* kpre = qkvh + QSZ;
  __half* vT   = qkvh + 2 * QSZ;
  unsigned short* xb  = (unsigned short*)(W + 12582912);
  unsigned short* ob  = xb;
  unsigned short* wqT = (unsigned short*)(W + 16777216);
  unsigned short* woT = wqT + 3 * 1024 * 1024;

  cvt_bf16<<<4096, 256, 0, stream>>>(x, xb);
  cvt_t<<<dim3(96, 32), 256, 0, stream>>>(Wqkv, wqT, 3072);
  cvt_t<<<dim3(32, 32), 256, 0, stream>>>(Wout, woT, 1024);
  // 1) QKV projection + fused RMSNorm/RoPE -> q/k f16 normed, v f16 transposed
  gemm_bf16<0><<<dim3(24, 64), 256, 0, stream>>>(xb, wqT, bqkv, nullptr, qkvh,
                                                 qs, ks);
  // 2) MFMA flash attention -> ob bf16 row-major
  attn_mfma<<<dim3(16, 128), 256, 0, stream>>>(qpre, kpre, vT, ob);
  // 3) output projection
  gemm_bf16<1><<<dim3(8, 64), 256, 0, stream>>>(ob, woT, bout, out, nullptr,
                                                nullptr, nullptr);
}

// Round 6
// 293.423 us; speedup vs baseline: 5.0767x; 1.0515x over previous
//
#include <hip/hip_runtime.h>
#include <hip/hip_bf16.h>
#include <hip/hip_fp16.h>
#include <math.h>

// B=8, H=16, N=1024, D=1024, hd=64
// ws layout (float units):
//   qpre f16 (B,H,N,64)   [0, 4M)        8M halfs   (normed+roped by gemm)
//   kpre f16 (B,H,N,64)   [4M, 8M)
//   vT   f16 (B,H,64,N)   [8M, 12M)      transposed per head
//   xb   bf16 [12M,16M)   (reused as ob after QKV gemm)
//   wqT  bf16 [16M,17.5M) ; woT bf16 [17.5M,18M)
// total 72 MB
#define QSZ 8388608  // halfs per q/k/v region

typedef short bf16x8 __attribute__((ext_vector_type(8)));
typedef _Float16 f16x8 __attribute__((ext_vector_type(8)));
typedef float f32x4 __attribute__((ext_vector_type(4)));

__device__ __forceinline__ unsigned short f2bf(float f) {
  __hip_bfloat16 h = __float2bfloat16(f);
  return *reinterpret_cast<unsigned short*>(&h);
}

__device__ __forceinline__ void gload16(const void* g, void* l) {
  __builtin_amdgcn_global_load_lds(
      (const __attribute__((address_space(1))) void*)g,
      (__attribute__((address_space(3))) void*)l, 16, 0, 0);
}

// ---------------------------------------------------------------------------
__global__ __launch_bounds__(256)
void cvt_bf16(const float* __restrict__ src, unsigned short* __restrict__ dst) {
  const int i = (blockIdx.x * 256 + threadIdx.x) * 8;
  const float4 a = *(const float4*)&src[i];
  const float4 b = *(const float4*)&src[i + 4];
  ushort4 lo, hi;
  lo.x = f2bf(a.x); lo.y = f2bf(a.y); lo.z = f2bf(a.z); lo.w = f2bf(a.w);
  hi.x = f2bf(b.x); hi.y = f2bf(b.y); hi.z = f2bf(b.z); hi.w = f2bf(b.w);
  *(ushort4*)&dst[i] = lo;
  *(ushort4*)&dst[i + 4] = hi;
}

// transpose+convert: src [1024,N] fp32 -> dst [N,1024] bf16
__global__ __launch_bounds__(256)
void cvt_t(const float* __restrict__ src, unsigned short* __restrict__ dst,
           const int N) {
  __shared__ unsigned short tile[32][33];
  const int k0 = blockIdx.y * 32, n0 = blockIdx.x * 32;
  const int t = threadIdx.x;
  const int r = t >> 3, c4 = (t & 7) * 4;
  const float4 v = *(const float4*)&src[(k0 + r) * N + n0 + c4];
  tile[r][c4 + 0] = f2bf(v.x);
  tile[r][c4 + 1] = f2bf(v.y);
  tile[r][c4 + 2] = f2bf(v.z);
  tile[r][c4 + 3] = f2bf(v.w);
  __syncthreads();
  ushort4 o;
  o.x = tile[c4 + 0][r];
  o.y = tile[c4 + 1][r];
  o.z = tile[c4 + 2][r];
  o.w = tile[c4 + 3][r];
  *(ushort4*)&dst[(long)(n0 + r) * 1024 + k0 + c4] = o;
}

// ---------------------------------------------------------------------------
// bf16 MFMA GEMM, single-barrier dbuf + XCD-stripe swizzle.
// Swizzle: flat = bx + by*GX; xcd = flat&7 (round-robin dispatch heuristic);
// j = flat>>3; bm = xcd*8 + (j&7), bn = j>>3. Each XCD works a contiguous
// 8-row bm stripe (A-stripe 2 MB resident in its 4 MiB L2); B streams once.
// MODE 0 (QKV, GX=24): fused RMSNorm + 2D-RoPE epilogue, q/k f16 (B,H,N,64),
//   v f16 transposed (B,H,64,N). MODE 1 (out-proj, GX=8): fp32 row-major.
// ---------------------------------------------------------------------------
template<int MODE, int GX>
__global__ __launch_bounds__(256)
void gemm_bf16(const unsigned short* __restrict__ A,
               const unsigned short* __restrict__ Bt,
               const float* __restrict__ bias, float* __restrict__ Cf,
               __half* __restrict__ Ch, const float* __restrict__ qsc,
               const float* __restrict__ ksc) {
  __shared__ __align__(16) unsigned short As[2][4096];
  __shared__ __align__(16) unsigned short Bs[2][4096];
  __shared__ float2 Tab[512];  // [pos 0..31][idx 0..15] cos/sin (MODE 0)
  const int t = threadIdx.x;
  const int flat = blockIdx.x + blockIdx.y * GX;
  const int xcd = flat & 7, j = flat >> 3;
  const int bm = xcd * 8 + (j & 7), bn = j >> 3;
  const int w = t >> 6, lane = t & 63;
  const int wm = (w & 1) << 6, wn = (w >> 1) << 6;
  const int lm = lane & 15, lk = (lane >> 4) << 3;

  if (MODE == 0) {  // build RoPE table (visible after first barrier)
    for (int e = t; e < 512; e += 256) {
      const int pos = e >> 4, idx = e & 15;
      const float invf = expf(-(float)idx * 0.57564627324851149f);
      const float ang = (float)pos * invf;
      Tab[e] = make_float2(cosf(ang), sinf(ang));
    }
  }

  const unsigned short* aptr =
      A + (long)(bm * 128 + (t >> 2)) * 1024 + ((t & 3) << 3);
  const unsigned short* bptr =
      Bt + (long)(bn * 128 + (t >> 2)) * 1024 + ((t & 3) << 3);

  f32x4 acc[4][4] = {};

  // prologue: stage k-tile 0 into buffer 0
  gload16(aptr, &As[0][t * 8]);
  gload16(aptr + 64 * 1024, &As[0][2048 + t * 8]);
  gload16(bptr, &Bs[0][t * 8]);
  gload16(bptr + 64 * 1024, &Bs[0][2048 + t * 8]);

  for (int it = 0; it < 32; ++it) {
    const int cur = it & 1;
    __syncthreads();  // drains this wave's vmcnt -> tile `it` staged for all
    if (it < 31) {    // prefetch tile it+1 into the other buffer
      const int nx = cur ^ 1;
      const int kk = (it + 1) * 32;
      gload16(aptr + kk, &As[nx][t * 8]);
      gload16(aptr + 64 * 1024 + kk, &As[nx][2048 + t * 8]);
      gload16(bptr + kk, &Bs[nx][t * 8]);
      gload16(bptr + 64 * 1024 + kk, &Bs[nx][2048 + t * 8]);
    }
    bf16x8 af[4], bfr[4];
#pragma unroll
    for (int mi = 0; mi < 4; ++mi)
      af[mi] = *(const bf16x8*)&As[cur][(wm + mi * 16 + lm) * 32 + lk];
#pragma unroll
    for (int ni = 0; ni < 4; ++ni)
      bfr[ni] = *(const bf16x8*)&Bs[cur][(wn + ni * 16 + lm) * 32 + lk];
#pragma unroll
    for (int mi = 0; mi < 4; ++mi)
#pragma unroll
      for (int ni = 0; ni < 4; ++ni)
        acc[mi][ni] = __builtin_amdgcn_mfma_f32_16x16x32_bf16(
            af[mi], bfr[ni], acc[mi][ni], 0, 0, 0);
  }

  const int r0 = (lane >> 4) << 2;  // q4*4
  const int nb = bn * 128 + wn;     // wave's col base

  if (MODE == 1) {
#pragma unroll
    for (int mi = 0; mi < 4; ++mi)
#pragma unroll
      for (int ni = 0; ni < 4; ++ni) {
        const int n = nb + ni * 16 + lm;
        const float bv = bias[n];
#pragma unroll
        for (int r = 0; r < 4; ++r)
          Cf[(long)(bm * 128 + wm + mi * 16 + r0 + r) * 1024 + n] =
              acc[mi][ni][r] + bv;
      }
    return;
  }

  // ---- MODE 0 fused epilogue ----
  const int tq = nb >> 10, h = (nb >> 6) & 15;
  if (tq == 2) {  // v: f16 transpose-scatter (B,H,64,N)
#pragma unroll
    for (int mi = 0; mi < 4; ++mi)
#pragma unroll
      for (int ni = 0; ni < 4; ++ni) {
        const int dd = ((nb + ni * 16 + lm) & 63);
        const float bv = bias[nb + ni * 16 + lm];
#pragma unroll
        for (int r = 0; r < 4; ++r) {
          const int m = bm * 128 + wm + mi * 16 + r0 + r;
          const int b = m >> 10, nn = m & 1023;
          Ch[2L * QSZ + ((long)((b * 16 + h) * 64 + dd)) * 1024 + nn] =
              __float2half(acc[mi][ni][r] + bv);
        }
      }
    return;
  }

  // q or k: RMSNorm + RoPE on f32 accs, then f16 store (B,H,N,64)
  const float* scp = (tq == 0) ? qsc : ksc;
  const float qmul = (tq == 0) ? 0.125f : 1.0f;  // fold hd^-0.5 into q
  float scv[4], bv[4];
#pragma unroll
  for (int ni = 0; ni < 4; ++ni) {
    scv[ni] = scp[ni * 16 + lm];
    bv[ni] = bias[nb + ni * 16 + lm];
  }
  __half* base = Ch + (long)tq * QSZ;
#pragma unroll
  for (int mi = 0; mi < 4; ++mi) {
#pragma unroll
    for (int r = 0; r < 4; ++r) {
      const float v0 = acc[mi][0][r] + bv[0];
      const float v1 = acc[mi][1][r] + bv[1];
      const float v2 = acc[mi][2][r] + bv[2];
      const float v3 = acc[mi][3][r] + bv[3];
      float ss = v0 * v0 + v1 * v1 + v2 * v2 + v3 * v3;
      ss += __shfl_xor(ss, 1, 64);
      ss += __shfl_xor(ss, 2, 64);
      ss += __shfl_xor(ss, 4, 64);
      ss += __shfl_xor(ss, 8, 64);
      const float inv = rsqrtf(ss * (1.0f / 64.0f) + 1e-6f) * qmul;
      const float a0 = v0 * inv * scv[0];
      const float a1 = v1 * inv * scv[1];
      const float a2 = v2 * inv * scv[2];
      const float a3 = v3 * inv * scv[3];
      const int m = bm * 128 + wm + mi * 16 + r0 + r;
      const int b = m >> 10, nn = m & 1023;
      const float2 tr = Tab[(nn >> 5) * 16 + lm];  // row-part angles
      const float2 tc = Tab[(nn & 31) * 16 + lm];  // col-part angles
      __half* row = base + ((long)((b * 16 + h) * 1024 + nn)) * 64 + lm;
      row[0]  = __float2half(a0 * tr.x - a2 * tr.y);
      row[16] = __float2half(a1 * tc.x - a3 * tc.y);
      row[32] = __float2half(a0 * tr.y + a2 * tr.x);
      row[48] = __float2half(a1 * tc.y + a3 * tc.x);
    }
  }
}

// ---------------------------------------------------------------------------
// MFMA flash attention (f16), fixed-offset softmax, single-barrier dbuf,
// 128 Q-rows per block (each wave: two sequential 16-row groups reusing its
// P strip), XCD swizzle so each XCD owns 16 heads (K/V working set = 4 MiB).
// ||q||=1 (0.125 folded), ||k||=8 -> s <= 8; p = exp(s-9).
// ---------------------------------------------------------------------------
__global__ __launch_bounds__(256)
void attn_mfma(const __half* __restrict__ qh, const __half* __restrict__ kh,
               const __half* __restrict__ vh, unsigned short* __restrict__ ob) {
  __shared__ __align__(16) __half Ks[2][4096];  // [krow][d] 64x64, swizzled
  __shared__ __align__(16) __half Vs[2][4096];  // [d][krow] 64x64, swizzled
  __shared__ __align__(16) __half Pl[4608];     // 4 waves x 16 x 72
  const int t = threadIdx.x;
  const int w = t >> 6, lane = t & 63;
  const int flat = blockIdx.x + blockIdx.y * 8;  // grid (8, 128)
  const int xcd = flat & 7, j = flat >> 3;       // j in [0,128)
  const int bh = xcd * 16 + (j >> 3);            // 16 heads per XCD
  const int qt = j & 7;                          // 128-row Q tile
  const int lm = lane & 15, q4 = lane >> 4;

  // Q A-frags for both row groups (q pre-scaled by 0.125)
  f16x8 qf[2][2];
#pragma unroll
  for (int g = 0; g < 2; ++g) {
    const __half* qrow =
        qh + ((long)(bh * 1024 + qt * 128 + g * 64 + w * 16 + lm)) * 64 +
        q4 * 8;
    qf[g][0] = *(const f16x8*)qrow;
    qf[g][1] = *(const f16x8*)(qrow + 32);
  }

  f32x4 o[2][4] = {};
  float l_r[2][4] = {};

  const int prow = t >> 3, pc = t & 7;
  const int scz = pc ^ (prow & 7);  // swizzled source chunk
  const __half* ksrc0 = kh + (long)(bh * 1024 + prow) * 64 + scz * 8;
  const __half* vsrc0 = vh + (long)(bh * 64 + prow) * 1024 + scz * 8;
  __half* Pw = Pl + w * 1152;

  gload16(ksrc0, &Ks[0][t * 8]);
  gload16(ksrc0 + 32 * 64, &Ks[0][2048 + t * 8]);
  gload16(vsrc0, &Vs[0][t * 8]);
  gload16(vsrc0 + 32 * 1024, &Vs[0][2048 + t * 8]);

  for (int kc = 0; kc < 16; ++kc) {
    const int cur = kc & 1;
    __syncthreads();  // chunk kc staged for all waves

    if (kc < 15) {
      const int nx = cur ^ 1;
      const __half* ksrc = ksrc0 + (kc + 1) * 4096;
      const __half* vsrc = vsrc0 + (kc + 1) * 64;
      gload16(ksrc, &Ks[nx][t * 8]);
      gload16(ksrc + 32 * 64, &Ks[nx][2048 + t * 8]);
      gload16(vsrc, &Vs[nx][t * 8]);
      gload16(vsrc + 32 * 1024, &Vs[nx][2048 + t * 8]);
    }

#pragma unroll
    for (int g = 0; g < 2; ++g) {
      // S = Q K^T; C layout: col=lm (krow), row=q4*4+reg
      f32x4 s[4];
#pragma unroll
      for (int nt = 0; nt < 4; ++nt) {
        s[nt] = (f32x4){0.f, 0.f, 0.f, 0.f};
        const int kr = nt * 16 + lm;
#pragma unroll
        for (int ks = 0; ks < 2; ++ks) {
          const f16x8 kf = *(const f16x8*)&Ks[cur][kr * 64 +
                                            (((ks << 2) + q4) ^ (kr & 7)) * 8];
          s[nt] = __builtin_amdgcn_mfma_f32_16x16x32_f16(qf[g][ks], kf, s[nt],
                                                         0, 0, 0);
        }
      }

      // fixed-offset softmax; P -> per-wave LDS strip (C -> A transform)
#pragma unroll
      for (int nt = 0; nt < 4; ++nt) {
#pragma unroll
        for (int r = 0; r < 4; ++r) {
          const float p = __expf(s[nt][r] - 9.0f);
          l_r[g][r] += p;
          Pw[(q4 * 4 + r) * 72 + nt * 16 + lm] = (__half)p;
        }
      }

      // O += P V (wave-internal LDS ordering; no barrier between groups)
#pragma unroll
      for (int ks2 = 0; ks2 < 2; ++ks2) {
        const f16x8 pf = *(const f16x8*)&Pw[lm * 72 + ks2 * 32 + q4 * 8];
#pragma unroll
        for (int nt = 0; nt < 4; ++nt) {
          const int dr = nt * 16 + lm;
          const f16x8 vf = *(const f16x8*)&Vs[cur][dr * 64 +
                                           (((ks2 << 2) + q4) ^ (dr & 7)) * 8];
          o[g][nt] = __builtin_amdgcn_mfma_f32_16x16x32_f16(pf, vf, o[g][nt],
                                                            0, 0, 0);
        }
      }
    }
  }

  const int b = bh >> 4, h = bh & 15;
#pragma unroll
  for (int g = 0; g < 2; ++g) {
#pragma unroll
    for (int r = 0; r < 4; ++r) {
      float l = l_r[g][r];
      l += __shfl_xor(l, 1, 64);
      l += __shfl_xor(l, 2, 64);
      l += __shfl_xor(l, 4, 64);
      l += __shfl_xor(l, 8, 64);
      const float linv = 1.0f / l;
      const long rowg =
          (long)(b * 1024 + qt * 128 + g * 64 + w * 16 + q4 * 4 + r) * 1024 +
          h * 64;
#pragma unroll
      for (int nt = 0; nt < 4; ++nt)
        ob[rowg + nt * 16 + lm] = f2bf(o[g][nt][r] * linv);
    }
  }
}

extern "C" void kernel_launch(void* const* d_in, const int* in_sizes, int n_in,
                              void* d_out, int out_size, void* d_ws,
                              size_t ws_size, hipStream_t stream) {
  const float* x    = (const float*)d_in[0];
  const float* Wqkv = (const float*)d_in[1];
  const float* bqkv = (const float*)d_in[2];
  const float* Wout = (const float*)d_in[3];
  const float* bout = (const float*)d_in[4];
  const float* qs   = (const float*)d_in[5];
  const float* ks   = (const float*)d_in[6];
  float* out = (float*)d_out;
  float* W = (float*)d_ws;  // 72 MB

  __half* qkvh = (__half*)W;            // q:0  k:+QSZ  vT:+2*QSZ (halfs)
  __half* qpre = qkvh;
  __half* kpre = qkvh + QSZ;
  __half* vT   = qkvh + 2 * QSZ;
  unsigned short* xb  = (unsigned short*)(W + 12582912);
  unsigned short* ob  = xb;
  unsigned short* wqT = (unsigned short*)(W + 16777216);
  unsigned short* woT = wqT + 3 * 1024 * 1024;

  cvt_bf16<<<4096, 256, 0, stream>>>(x, xb);
  cvt_t<<<dim3(96, 32), 256, 0, stream>>>(Wqkv, wqT, 3072);
  cvt_t<<<dim3(32, 32), 256, 0, stream>>>(Wout, woT, 1024);
  // 1) QKV projection + fused RMSNorm/RoPE -> q/k f16 normed, v f16 transposed
  gemm_bf16<0, 24><<<dim3(24, 64), 256, 0, stream>>>(xb, wqT, bqkv, nullptr,
                                                     qkvh, qs, ks);
  // 2) MFMA flash attention (128-row blocks) -> ob bf16 row-major
  attn_mfma<<<dim3(8, 128), 256, 0, stream>>>(qpre, kpre, vT, ob);
  // 3) output projection
  gemm_bf16<1, 8><<<dim3(8, 64), 256, 0, stream>>>(ob, woT, bout, out, nullptr,
                                                   nullptr, nullptr);
}